// Round 5
// baseline (457.241 us; speedup 1.0000x reference)
//
#include <hip/hip_runtime.h>
#include <stdint.h>

typedef __attribute__((ext_vector_type(8))) short bf16x8;
typedef __attribute__((ext_vector_type(4))) float f32x4;
typedef unsigned short u16;
typedef unsigned int u32;

#define NLVL 16
#define NNODE 16384
#define MPL 1024
#define DIN 1024
#define DH 256
#define NCTR 16  // barrier sub-counters, 128B apart

__device__ __forceinline__ u16 f2bf(float f) {
  u32 u = __builtin_bit_cast(u32, f);
  u += 0x7FFFu + ((u >> 16) & 1u);
  return (u16)(u >> 16);
}
__device__ __forceinline__ float b2f(u16 h) {
  u32 u = ((u32)h) << 16;
  return __builtin_bit_cast(float, u);
}
__device__ __forceinline__ float fsig(float x) {
  return __builtin_amdgcn_rcpf(1.0f + __expf(-x));
}
__device__ __forceinline__ float ftanh(float x) {
  return 1.0f - 2.0f * __builtin_amdgcn_rcpf(__expf(2.0f * x) + 1.0f);
}

__device__ __forceinline__ void async_copy16(const void* g, void* lds) {
  __builtin_amdgcn_global_load_lds((const __attribute__((address_space(1))) void*)g,
                                   (__attribute__((address_space(3))) void*)lds, 16, 0, 0);
}

// ---------------- conversion kernels ----------------
__global__ __launch_bounds__(256) void k_cvt_x(const float* __restrict__ x,
                                               u16* __restrict__ xb) {
  size_t i = (size_t)blockIdx.x * 256 + threadIdx.x;  // one thread = 8 elems
  const float4* p = (const float4*)x + i * 2;
  float4 v0 = p[0], v1 = p[1];
  union { u16 s[8]; uint4 v; } o;
  o.s[0] = f2bf(v0.x); o.s[1] = f2bf(v0.y); o.s[2] = f2bf(v0.z); o.s[3] = f2bf(v0.w);
  o.s[4] = f2bf(v1.x); o.s[5] = f2bf(v1.y); o.s[6] = f2bf(v1.z); o.s[7] = f2bf(v1.w);
  *((uint4*)(xb + i * 8)) = o.v;
}

__global__ __launch_bounds__(256) void k_cvt_w(
    const float* __restrict__ Wioux, const float* __restrict__ Wfx,
    const float* __restrict__ Wiouh, const float* __restrict__ Wfh,
    const float* __restrict__ bioux, const float* __restrict__ bfx,
    const float* __restrict__ biouh, const float* __restrict__ bfh,
    u16* __restrict__ Wxb, u16* __restrict__ Whb,
    float* __restrict__ b1, float* __restrict__ b2) {
  int t = blockIdx.x * 256 + threadIdx.x;
  if (t < 131072) {  // Wxb [1024][1024] bf16
    int idx = t * 8;
    int row = idx >> 10, col = idx & 1023;
    const float* src = (row < 768) ? (Wioux + (size_t)row * 1024 + col)
                                   : (Wfx + (size_t)(row - 768) * 1024 + col);
    union { u16 s[8]; uint4 v; } o;
#pragma unroll
    for (int j = 0; j < 8; ++j) o.s[j] = f2bf(src[j]);
    *((uint4*)(Wxb + idx)) = o.v;
  } else if (t < 163840) {  // Whb [1024][256] bf16
    int idx = (t - 131072) * 8;
    int row = idx >> 8, col = idx & 255;
    const float* src = (row < 768) ? (Wiouh + (size_t)row * 256 + col)
                                   : (Wfh + (size_t)(row - 768) * 256 + col);
    union { u16 s[8]; uint4 v; } o;
#pragma unroll
    for (int j = 0; j < 8; ++j) o.s[j] = f2bf(src[j]);
    *((uint4*)(Whb + idx)) = o.v;
  } else if (t < 164096) {  // biases
    int idx = (t - 163840) * 8;
#pragma unroll
    for (int j = 0; j < 8; ++j) {
      int i = idx + j;
      if (i < 1024) b1[i] = (i < 768) ? bioux[i] : bfx[i - 768];
      else { int k = i - 1024; b2[k] = (k < 768) ? biouh[k] : bfh[k - 768]; }
    }
  }
}

// ---------------- phase 1: fused gate-preact GEMM ----------------
// gx[16384][1024] = xb[16384][1024] @ Wxb[1024][1024]^T + bias1
__device__ __forceinline__ int swz2(int row) { return (row & 3) ^ ((row >> 2) & 3); }

__global__ __launch_bounds__(256) void k_gemm1(const u16* __restrict__ xb,
                                               const u16* __restrict__ Wxb,
                                               const float* __restrict__ b1,
                                               float* __restrict__ gx) {
  __shared__ __align__(16) u16 As[2][4096];  // [128][32] bf16, chunk-swizzled
  __shared__ __align__(16) u16 Bs[2][4096];
  const int tid = threadIdx.x, w = tid >> 6, l = tid & 63;
  const int tM = blockIdx.y * 128, tN = blockIdx.x * 128;
  const int wm = w >> 1, wn = w & 1;

  f32x4 acc[4][4];
#pragma unroll
  for (int mt = 0; mt < 4; ++mt)
#pragma unroll
    for (int nt = 0; nt < 4; ++nt) acc[mt][nt] = (f32x4){0.f, 0.f, 0.f, 0.f};

  auto stage = [&](int buf, int t) {
    int k0 = t * 32;
#pragma unroll
    for (int i = 0; i < 2; ++i) {
      int seg = w * 2 + i;
      int row = seg * 16 + (l >> 2);
      int qg = (l & 3) ^ swz2(row);
      async_copy16(xb + (size_t)(tM + row) * 1024 + k0 + qg * 8, &As[buf][seg * 512]);
      async_copy16(Wxb + (size_t)(tN + row) * 1024 + k0 + qg * 8, &Bs[buf][seg * 512]);
    }
  };

  auto compute = [&](int buf) {
    bf16x8 a[4], b[4];
#pragma unroll
    for (int mt = 0; mt < 4; ++mt) {
      int row = wm * 64 + mt * 16 + (l & 15);
      int cs = (l >> 4) ^ swz2(row);
      a[mt] = *(const bf16x8*)&As[buf][row * 32 + cs * 8];
    }
#pragma unroll
    for (int nt = 0; nt < 4; ++nt) {
      int row = wn * 64 + nt * 16 + (l & 15);
      int cs = (l >> 4) ^ swz2(row);
      b[nt] = *(const bf16x8*)&Bs[buf][row * 32 + cs * 8];
    }
#pragma unroll
    for (int mt = 0; mt < 4; ++mt)
#pragma unroll
      for (int nt = 0; nt < 4; ++nt)
        acc[mt][nt] = __builtin_amdgcn_mfma_f32_16x16x32_bf16(a[mt], b[nt], acc[mt][nt], 0, 0, 0);
  };

  stage(0, 0);
  __syncthreads();
  int buf = 0;
  for (int t = 0; t < 32; ++t) {
    if (t + 1 < 32) stage(buf ^ 1, t + 1);
    compute(buf);
    __syncthreads();
    buf ^= 1;
  }

#pragma unroll
  for (int mt = 0; mt < 4; ++mt)
#pragma unroll
    for (int nt = 0; nt < 4; ++nt) {
      int col = tN + wn * 64 + nt * 16 + (l & 15);
      float bias = b1[col];
      int rbase = tM + wm * 64 + mt * 16 + (l >> 4) * 4;
#pragma unroll
      for (int r = 0; r < 4; ++r)
        gx[(size_t)(rbase + r) * 1024 + col] = acc[mt][nt][r] + bias;
    }
}

// ---------------- phase 2: persistent megakernel over all 16 levels ----------------
// Grid: 256 blocks — block b: node-tile (b & 63) x hidden-col group (b >> 6, 64 cols).
// Whb B-fragments for both small GEMMs live in registers across all levels.
//
// Grid barrier (master/broadcast): arrivals on 16 spread counters (relaxed agent
// add). ONLY block 0 polls the counters; when sum == round*256 it stores a single
// broadcast flag. All other leaders poll that one line (relaxed agent load +
// s_sleep backoff) -> 16x less LLC poll traffic than all-poll-all. Per-block
// release/acquire agent fences provide cross-XCD data visibility.
__device__ __forceinline__ void grid_barrier(unsigned* bar, unsigned round) {
  __syncthreads();
  if (threadIdx.x == 0) {
    __builtin_amdgcn_fence(__ATOMIC_RELEASE, "agent");  // vmcnt0 + L2 writeback
    unsigned* ctr = bar + (blockIdx.x & (NCTR - 1)) * 32;  // 128B apart
    __hip_atomic_fetch_add(ctr, 1u, __ATOMIC_RELAXED, __HIP_MEMORY_SCOPE_AGENT);
    unsigned* flag = bar + NCTR * 32;  // own cache line
    if (blockIdx.x == 0) {
      const unsigned target = round * 256u;
      for (;;) {
        unsigned s = 0;
#pragma unroll
        for (int i = 0; i < NCTR; ++i)
          s += __hip_atomic_load(bar + i * 32, __ATOMIC_RELAXED, __HIP_MEMORY_SCOPE_AGENT);
        if (s >= target) break;
        __builtin_amdgcn_s_sleep(2);
      }
      __hip_atomic_store(flag, round, __ATOMIC_RELAXED, __HIP_MEMORY_SCOPE_AGENT);
    } else {
      while (__hip_atomic_load(flag, __ATOMIC_RELAXED, __HIP_MEMORY_SCOPE_AGENT) < round)
        __builtin_amdgcn_s_sleep(8);
    }
    __builtin_amdgcn_fence(__ATOMIC_ACQUIRE, "agent");  // invalidate stale L1/L2
  }
  __syncthreads();
}

__global__ __launch_bounds__(256, 1) void k_levels(
    const int* __restrict__ children, const float* __restrict__ gx,
    const u16* __restrict__ Whb, const float* __restrict__ b2,
    u16* __restrict__ hb, float* __restrict__ cb,
    float* __restrict__ hout, unsigned* __restrict__ bar) {
  __shared__ int ch[64];
  __shared__ __align__(16) u16 hch[64 * 256];   // child rows, swizzled
  __shared__ __align__(16) u16 hsum[16 * 256];  // child-sum rows, swizzled
  __shared__ float iouA[16 * 196];              // activated i,o,u (3x64, pad 196)
  const int tid = threadIdx.x, w = tid >> 6, l = tid & 63;
  const int ntile = blockIdx.x & 63;
  const int h0 = (blockIdx.x >> 6) * 64;  // hidden-col range [h0, h0+64)

  // ---- hoist Whb fragments + biases into registers (live across all levels) ----
  bf16x8 w1[3][8];  // GEMM1 (iou) tiles: wave w covers tiles w*3 .. w*3+2
  int colg_[3]; float b1g_[3];
#pragma unroll
  for (int i = 0; i < 3; ++i) {
    int tt = w * 3 + i;
    int s = tt >> 2, t = tt & 3;
    int colg = s * 256 + h0 + t * 16 + (l & 15);
    colg_[i] = colg;
    b1g_[i] = b2[colg];
    const u16* bp = Whb + (size_t)colg * 256 + (l >> 4) * 8;
#pragma unroll
    for (int ks = 0; ks < 8; ++ks) w1[i][ks] = *(const bf16x8*)(bp + ks * 32);
  }
  bf16x8 w2[4][8];  // GEMM2 (forget) tiles
  int col2_[4]; float b2g_[4];
#pragma unroll
  for (int nt = 0; nt < 4; ++nt) {
    int hcol = h0 + nt * 16 + (l & 15);
    col2_[nt] = hcol;
    b2g_[nt] = b2[768 + hcol];
    const u16* bp = Whb + (size_t)(768 + hcol) * 256 + (l >> 4) * 8;
#pragma unroll
    for (int ks = 0; ks < 8; ++ks) w2[nt][ks] = *(const bf16x8*)(bp + ks * 32);
  }

  for (int level = 0; level < NLVL; ++level) {
    const int node0 = level * 1024 + ntile * 16;
    if (tid < 64) ch[tid] = children[node0 * 4 + tid];
    __syncthreads();

    // gather child h rows (bf16), zero for absent children; swizzled store
#pragma unroll
    for (int it = 0; it < 8; ++it) {
      int id = tid + it * 256;
      int row = id >> 5, q = id & 31;
      int child = ch[row];
      uint4 v = make_uint4(0u, 0u, 0u, 0u);
      if (child >= 0) v = *(const uint4*)(hb + (size_t)child * 256 + q * 8);
      *(uint4*)&hch[row * 256 + ((q ^ (row & 7)) * 8)] = v;
    }
    __syncthreads();

    // hsum: f32 accumulate over 4 children, stored bf16 swizzled
#pragma unroll
    for (int it = 0; it < 2; ++it) {
      int id = tid + it * 256;
      int row = id >> 5, q = id & 31;
      float s[8] = {0.f, 0.f, 0.f, 0.f, 0.f, 0.f, 0.f, 0.f};
#pragma unroll
      for (int k = 0; k < 4; ++k) {
        int hr = row * 4 + k;
        bf16x8 v = *(const bf16x8*)&hch[hr * 256 + ((q ^ (hr & 7)) * 8)];
#pragma unroll
        for (int j = 0; j < 8; ++j) s[j] += b2f((u16)v[j]);
      }
      union { u16 us[8]; uint4 v4; } o;
#pragma unroll
      for (int j = 0; j < 8; ++j) o.us[j] = f2bf(s[j]);
      *(uint4*)&hsum[row * 256 + ((q ^ (row & 7)) * 8)] = o.v4;
    }
    __syncthreads();

    // GEMM1: iou tiles (3 per wave), B-operands from registers
    bf16x8 a1[8];
    {
      int arow = l & 15;
#pragma unroll
      for (int ks = 0; ks < 8; ++ks) {
        int chunk = ks * 4 + (l >> 4);
        a1[ks] = *(const bf16x8*)&hsum[arow * 256 + ((chunk ^ (arow & 7)) * 8)];
      }
    }
#pragma unroll
    for (int i = 0; i < 3; ++i) {
      int tt = w * 3 + i;
      int s = tt >> 2, t = tt & 3;
      f32x4 acc = (f32x4){0.f, 0.f, 0.f, 0.f};
#pragma unroll
      for (int ks = 0; ks < 8; ++ks)
        acc = __builtin_amdgcn_mfma_f32_16x16x32_bf16(a1[ks], w1[i][ks], acc, 0, 0, 0);
      int colg = colg_[i];
      float bias = b1g_[i];
#pragma unroll
      for (int r = 0; r < 4; ++r) {
        int nodeL = (l >> 4) * 4 + r;
        float v = acc[r] + gx[(size_t)(node0 + nodeL) * 1024 + colg] + bias;
        iouA[nodeL * 196 + s * 64 + t * 16 + (l & 15)] = (s < 2) ? fsig(v) : ftanh(v);
      }
    }
    __syncthreads();

    // GEMM2 (per-child forget gates) + combine. Wave w: child rows [w*16, w*16+16).
    bf16x8 a2[8];
    {
      int arow = w * 16 + (l & 15);
#pragma unroll
      for (int ks = 0; ks < 8; ++ks) {
        int chunk = ks * 4 + (l >> 4);
        a2[ks] = *(const bf16x8*)&hch[arow * 256 + ((chunk ^ (arow & 7)) * 8)];
      }
    }
    const int nodeL = w * 4 + (l >> 4);
    const int node = node0 + nodeL;
#pragma unroll
    for (int nt = 0; nt < 4; ++nt) {
      int hl = nt * 16 + (l & 15);  // local h 0..63
      int hcol = col2_[nt];         // = h0 + hl
      f32x4 acc = (f32x4){0.f, 0.f, 0.f, 0.f};
#pragma unroll
      for (int ks = 0; ks < 8; ++ks)
        acc = __builtin_amdgcn_mfma_f32_16x16x32_bf16(a2[ks], w2[nt][ks], acc, 0, 0, 0);
      float fx = gx[(size_t)node * 1024 + 768 + hcol] + b2g_[nt];
      float fcsum = 0.f;
#pragma unroll
      for (int r = 0; r < 4; ++r) {
        int child = ch[nodeL * 4 + r];
        if (child >= 0) {
          float cch = cb[(size_t)child * 256 + hcol];
          fcsum += fsig(fx + acc[r]) * cch;
        }
      }
      float ig = iouA[nodeL * 196 + hl];
      float og = iouA[nodeL * 196 + 64 + hl];
      float ug = iouA[nodeL * 196 + 128 + hl];
      float cnew = ig * ug + fcsum;
      float hnew = og * ftanh(cnew);
      cb[(size_t)node * 256 + hcol] = cnew;
      hout[(size_t)node * 256 + hcol] = hnew;
      hb[(size_t)node * 256 + hcol] = f2bf(hnew);
    }

    if (level + 1 < NLVL) grid_barrier(bar, (unsigned)(level + 1));
  }
}

// ---------------- launch ----------------
extern "C" void kernel_launch(void* const* d_in, const int* in_sizes, int n_in,
                              void* d_out, int out_size, void* d_ws, size_t ws_size,
                              hipStream_t stream) {
  const float* x = (const float*)d_in[0];
  const int* children = (const int*)d_in[1];
  const float* Wioux = (const float*)d_in[2];
  const float* bioux = (const float*)d_in[3];
  const float* Wiouh = (const float*)d_in[4];
  const float* biouh = (const float*)d_in[5];
  const float* Wfx = (const float*)d_in[6];
  const float* bfx = (const float*)d_in[7];
  const float* Wfh = (const float*)d_in[8];
  const float* bfh = (const float*)d_in[9];

  char* ws = (char*)d_ws;
  u16* xb = (u16*)(ws + 0);              // 33,554,432 B
  float* gx = (float*)(ws + 33554432);   // 67,108,864 B
  u16* hb = (u16*)(ws + 100663296);      //  8,388,608 B
  float* cb = (float*)(ws + 109051904);  // 16,777,216 B
  u16* Wxb = (u16*)(ws + 125829120);     //  2,097,152 B
  u16* Whb = (u16*)(ws + 127926272);     //    524,288 B
  float* b1 = (float*)(ws + 128450560);  //      4,096 B
  float* b2 = (float*)(ws + 128454656);  //      4,096 B
  unsigned* bar = (unsigned*)(ws + 128458752);  // 16 ctrs x 128 B + flag line
  float* hout = (float*)d_out;

  hipMemsetAsync(bar, 0, 4096, stream);
  k_cvt_x<<<8192, 256, 0, stream>>>(x, xb);
  k_cvt_w<<<641, 256, 0, stream>>>(Wioux, Wfx, Wiouh, Wfh, bioux, bfx, biouh, bfh,
                                   Wxb, Whb, b1, b2);
  k_gemm1<<<dim3(8, 128), 256, 0, stream>>>(xb, Wxb, b1, gx);
  k_levels<<<256, 256, 0, stream>>>(children, gx, Whb, b2, hb, cb, hout, bar);
}

// Round 7
// 285.821 us; speedup vs baseline: 1.5997x; 1.5997x over previous
//
#include <hip/hip_runtime.h>
#include <stdint.h>

typedef __attribute__((ext_vector_type(8))) short bf16x8;
typedef __attribute__((ext_vector_type(4))) float f32x4;
typedef __attribute__((ext_vector_type(4))) unsigned int u32x4;
typedef unsigned short u16;
typedef unsigned int u32;

#define NLVL 16
#define NNODE 16384
#define MPL 1024
#define DIN 1024
#define DH 256

__device__ __forceinline__ u16 f2bf(float f) {
  u32 u = __builtin_bit_cast(u32, f);
  u += 0x7FFFu + ((u >> 16) & 1u);
  return (u16)(u >> 16);
}
__device__ __forceinline__ float b2f(u16 h) {
  u32 u = ((u32)h) << 16;
  return __builtin_bit_cast(float, u);
}
__device__ __forceinline__ float fsig(float x) {
  return __builtin_amdgcn_rcpf(1.0f + __expf(-x));
}
__device__ __forceinline__ float ftanh(float x) {
  return 1.0f - 2.0f * __builtin_amdgcn_rcpf(__expf(2.0f * x) + 1.0f);
}

__device__ __forceinline__ void async_copy16(const void* g, void* lds) {
  __builtin_amdgcn_global_load_lds((const __attribute__((address_space(1))) void*)g,
                                   (__attribute__((address_space(3))) void*)lds, 16, 0, 0);
}

// L2-bypass (coherence-point) access: sc0 sc1 = agent-scope, skips L1+L2 so
// cross-block/cross-XCD message passing needs no cache-wide fences.
__device__ __forceinline__ void gload_x4(u32x4& v, const void* p) {
  asm volatile("global_load_dwordx4 %0, %1, off sc0 sc1" : "=&v"(v) : "v"(p));
}
__device__ __forceinline__ void gstore_dw(float* p, float v) {
  asm volatile("global_store_dword %0, %1, off sc0 sc1" :: "v"(p), "v"(v) : "memory");
}
__device__ __forceinline__ void gstore_sh(u16* p, u16 v) {
  u32 w = v;
  asm volatile("global_store_short %0, %1, off sc0 sc1" :: "v"(p), "v"(w) : "memory");
}

// ---------------- conversion kernels ----------------
__global__ __launch_bounds__(256) void k_cvt_x(const float* __restrict__ x,
                                               u16* __restrict__ xb) {
  size_t i = (size_t)blockIdx.x * 256 + threadIdx.x;  // one thread = 8 elems
  const float4* p = (const float4*)x + i * 2;
  float4 v0 = p[0], v1 = p[1];
  union { u16 s[8]; uint4 v; } o;
  o.s[0] = f2bf(v0.x); o.s[1] = f2bf(v0.y); o.s[2] = f2bf(v0.z); o.s[3] = f2bf(v0.w);
  o.s[4] = f2bf(v1.x); o.s[5] = f2bf(v1.y); o.s[6] = f2bf(v1.z); o.s[7] = f2bf(v1.w);
  *((uint4*)(xb + i * 8)) = o.v;
}

__global__ __launch_bounds__(256) void k_cvt_w(
    const float* __restrict__ Wioux, const float* __restrict__ Wfx,
    const float* __restrict__ Wiouh, const float* __restrict__ Wfh,
    const float* __restrict__ bioux, const float* __restrict__ bfx,
    const float* __restrict__ biouh, const float* __restrict__ bfh,
    u16* __restrict__ Wxb, u16* __restrict__ Whb,
    float* __restrict__ b1, float* __restrict__ b2) {
  int t = blockIdx.x * 256 + threadIdx.x;
  if (t < 131072) {  // Wxb [1024][1024] bf16
    int idx = t * 8;
    int row = idx >> 10, col = idx & 1023;
    const float* src = (row < 768) ? (Wioux + (size_t)row * 1024 + col)
                                   : (Wfx + (size_t)(row - 768) * 1024 + col);
    union { u16 s[8]; uint4 v; } o;
#pragma unroll
    for (int j = 0; j < 8; ++j) o.s[j] = f2bf(src[j]);
    *((uint4*)(Wxb + idx)) = o.v;
  } else if (t < 163840) {  // Whb [1024][256] bf16
    int idx = (t - 131072) * 8;
    int row = idx >> 8, col = idx & 255;
    const float* src = (row < 768) ? (Wiouh + (size_t)row * 256 + col)
                                   : (Wfh + (size_t)(row - 768) * 256 + col);
    union { u16 s[8]; uint4 v; } o;
#pragma unroll
    for (int j = 0; j < 8; ++j) o.s[j] = f2bf(src[j]);
    *((uint4*)(Whb + idx)) = o.v;
  } else if (t < 164096) {  // biases
    int idx = (t - 163840) * 8;
#pragma unroll
    for (int j = 0; j < 8; ++j) {
      int i = idx + j;
      if (i < 1024) b1[i] = (i < 768) ? bioux[i] : bfx[i - 768];
      else { int k = i - 1024; b2[k] = (k < 768) ? biouh[k] : bfh[k - 768]; }
    }
  }
}

// ---------------- phase 1: fused gate-preact GEMM ----------------
// gx[16384][1024] = xb[16384][1024] @ Wxb[1024][1024]^T + bias1
__device__ __forceinline__ int swz2(int row) { return (row & 3) ^ ((row >> 2) & 3); }

__global__ __launch_bounds__(256) void k_gemm1(const u16* __restrict__ xb,
                                               const u16* __restrict__ Wxb,
                                               const float* __restrict__ b1,
                                               float* __restrict__ gx) {
  __shared__ __align__(16) u16 As[2][4096];  // [128][32] bf16, chunk-swizzled
  __shared__ __align__(16) u16 Bs[2][4096];
  const int tid = threadIdx.x, w = tid >> 6, l = tid & 63;
  const int tM = blockIdx.y * 128, tN = blockIdx.x * 128;
  const int wm = w >> 1, wn = w & 1;

  f32x4 acc[4][4];
#pragma unroll
  for (int mt = 0; mt < 4; ++mt)
#pragma unroll
    for (int nt = 0; nt < 4; ++nt) acc[mt][nt] = (f32x4){0.f, 0.f, 0.f, 0.f};

  auto stage = [&](int buf, int t) {
    int k0 = t * 32;
#pragma unroll
    for (int i = 0; i < 2; ++i) {
      int seg = w * 2 + i;
      int row = seg * 16 + (l >> 2);
      int qg = (l & 3) ^ swz2(row);
      async_copy16(xb + (size_t)(tM + row) * 1024 + k0 + qg * 8, &As[buf][seg * 512]);
      async_copy16(Wxb + (size_t)(tN + row) * 1024 + k0 + qg * 8, &Bs[buf][seg * 512]);
    }
  };

  auto compute = [&](int buf) {
    bf16x8 a[4], b[4];
#pragma unroll
    for (int mt = 0; mt < 4; ++mt) {
      int row = wm * 64 + mt * 16 + (l & 15);
      int cs = (l >> 4) ^ swz2(row);
      a[mt] = *(const bf16x8*)&As[buf][row * 32 + cs * 8];
    }
#pragma unroll
    for (int nt = 0; nt < 4; ++nt) {
      int row = wn * 64 + nt * 16 + (l & 15);
      int cs = (l >> 4) ^ swz2(row);
      b[nt] = *(const bf16x8*)&Bs[buf][row * 32 + cs * 8];
    }
#pragma unroll
    for (int mt = 0; mt < 4; ++mt)
#pragma unroll
      for (int nt = 0; nt < 4; ++nt)
        acc[mt][nt] = __builtin_amdgcn_mfma_f32_16x16x32_bf16(a[mt], b[nt], acc[mt][nt], 0, 0, 0);
  };

  stage(0, 0);
  __syncthreads();
  int buf = 0;
  for (int t = 0; t < 32; ++t) {
    if (t + 1 < 32) stage(buf ^ 1, t + 1);
    compute(buf);
    __syncthreads();
    buf ^= 1;
  }

#pragma unroll
  for (int mt = 0; mt < 4; ++mt)
#pragma unroll
    for (int nt = 0; nt < 4; ++nt) {
      int col = tN + wn * 64 + nt * 16 + (l & 15);
      float bias = b1[col];
      int rbase = tM + wm * 64 + mt * 16 + (l >> 4) * 4;
#pragma unroll
      for (int r = 0; r < 4; ++r)
        gx[(size_t)(rbase + r) * 1024 + col] = acc[mt][nt][r] + bias;
    }
}

// ---------------- phase 2: persistent dataflow kernel over all 16 levels ----------------
// 256 blocks, 1/CU — block b handles (tile = b&63, colgrp = b>>6) at every level.
// NO global barrier. Per-tile completion flags (4 producers each); consumers poll
// only the child tiles they need. h/c cross-block data moves via sc0sc1 (L2-bypass)
// loads/stores -> no cache-maintenance fences, no straggler serialization.
__global__ __launch_bounds__(256, 1) void k_levels(
    const int* __restrict__ children, const float* __restrict__ gx,
    const u16* __restrict__ Whb, const float* __restrict__ b2,
    u16* __restrict__ hb, float* __restrict__ cb,
    float* __restrict__ hout, u32* __restrict__ flags) {
  __shared__ int ch[64];
  __shared__ __align__(16) u16 hch[64 * 256];   // child h rows, swizzled (32 KB)
  __shared__ __align__(16) u16 hsum[16 * 256];  // child-sum rows, swizzled (8 KB)
  __shared__ __align__(16) float c_lds[64 * 68]; // child c slice, padded (17 KB)
  __shared__ float iouA[16 * 196];              // activated i,o,u (12.5 KB)
  const int tid = threadIdx.x, w = tid >> 6, l = tid & 63;
  const int ntile = blockIdx.x & 63;
  const int h0 = (blockIdx.x >> 6) * 64;  // hidden-col range [h0, h0+64)

  // ---- hoist Whb fragments + biases into registers (live across all levels) ----
  bf16x8 w1[3][8];  // GEMM1 (iou) tiles: wave w covers tiles w*3 .. w*3+2
  int colg_[3]; float b1g_[3];
#pragma unroll
  for (int i = 0; i < 3; ++i) {
    int tt = w * 3 + i;
    int s = tt >> 2, t = tt & 3;
    int colg = s * 256 + h0 + t * 16 + (l & 15);
    colg_[i] = colg;
    b1g_[i] = b2[colg];
    const u16* bp = Whb + (size_t)colg * 256 + (l >> 4) * 8;
#pragma unroll
    for (int ks = 0; ks < 8; ++ks) w1[i][ks] = *(const bf16x8*)(bp + ks * 32);
  }
  bf16x8 w2[4][8];  // GEMM2 (forget) tiles
  float b2g_[4];
#pragma unroll
  for (int nt = 0; nt < 4; ++nt) {
    int hcol = h0 + nt * 16 + (l & 15);
    b2g_[nt] = b2[768 + hcol];
    const u16* bp = Whb + (size_t)(768 + hcol) * 256 + (l >> 4) * 8;
#pragma unroll
    for (int ks = 0; ks < 8; ++ks) w2[nt][ks] = *(const bf16x8*)(bp + ks * 32);
  }

  for (int level = 0; level < NLVL; ++level) {
    const int node0 = level * 1024 + ntile * 16;
    if (tid < 64) ch[tid] = children[node0 * 4 + tid];
    __syncthreads();

    // ---- wait for producer tiles (64 lanes poll in parallel, backoff spin) ----
    if (level > 0 && tid < 64) {
      int child = ch[tid];
      if (child >= 0) {
        const u32* f = flags + (child >> 4);
        while (__hip_atomic_load(f, __ATOMIC_RELAXED, __HIP_MEMORY_SCOPE_AGENT) < 4u)
          __builtin_amdgcn_s_sleep(16);
      }
    }
    __syncthreads();

    // ---- gather child h rows (bf16) + c slice (f32) via L2-bypass loads ----
    u32x4 hv[8]; int hc[8];
#pragma unroll
    for (int it = 0; it < 8; ++it) {
      int id = tid + it * 256;
      int row = id >> 5, q = id & 31;
      int child = ch[row]; hc[it] = child;
      int cr = child < 0 ? 0 : child;
      gload_x4(hv[it], hb + (size_t)cr * 256 + q * 8);
    }
    // c slice: 64 child rows x 16 quads (4 floats each) = 1024 ids, 4 iters x 256
    u32x4 cv[4]; int cc[4];
#pragma unroll
    for (int it = 0; it < 4; ++it) {
      int id = tid + it * 256;
      int row = id >> 4, qq = id & 15;
      int child = ch[row]; cc[it] = child;
      int cr = child < 0 ? 0 : child;
      gload_x4(cv[it], cb + (size_t)cr * 256 + h0 + qq * 4);
    }
    asm volatile("s_waitcnt vmcnt(0)"
                 : "+v"(hv[0]), "+v"(hv[1]), "+v"(hv[2]), "+v"(hv[3]),
                   "+v"(hv[4]), "+v"(hv[5]), "+v"(hv[6]), "+v"(hv[7]),
                   "+v"(cv[0]), "+v"(cv[1]), "+v"(cv[2]), "+v"(cv[3]) :: "memory");
    __builtin_amdgcn_sched_barrier(0);
#pragma unroll
    for (int it = 0; it < 8; ++it) {
      int id = tid + it * 256;
      int row = id >> 5, q = id & 31;
      u32x4 v = hv[it];
      if (hc[it] < 0) v = (u32x4){0u, 0u, 0u, 0u};
      *(u32x4*)&hch[row * 256 + ((q ^ (row & 7)) * 8)] = v;
    }
#pragma unroll
    for (int it = 0; it < 4; ++it) {
      int id = tid + it * 256;
      int row = id >> 4, qq = id & 15;
      u32x4 v = cv[it];
      if (cc[it] < 0) v = (u32x4){0u, 0u, 0u, 0u};
      *(u32x4*)&c_lds[row * 68 + qq * 4] = v;
    }
    __syncthreads();

    // ---- hsum: f32 accumulate over 4 children, stored bf16 swizzled ----
#pragma unroll
    for (int it = 0; it < 2; ++it) {
      int id = tid + it * 256;
      int row = id >> 5, q = id & 31;
      float s[8] = {0.f, 0.f, 0.f, 0.f, 0.f, 0.f, 0.f, 0.f};
#pragma unroll
      for (int k = 0; k < 4; ++k) {
        int hr = row * 4 + k;
        bf16x8 v = *(const bf16x8*)&hch[hr * 256 + ((q ^ (hr & 7)) * 8)];
#pragma unroll
        for (int j = 0; j < 8; ++j) s[j] += b2f((u16)v[j]);
      }
      union { u16 us[8]; u32x4 v4; } o;
#pragma unroll
      for (int j = 0; j < 8; ++j) o.us[j] = f2bf(s[j]);
      *(u32x4*)&hsum[row * 256 + ((q ^ (row & 7)) * 8)] = o.v4;
    }
    __syncthreads();

    // ---- GEMM1: iou tiles (3 per wave), B-operands from registers ----
    bf16x8 a1[8];
    {
      int arow = l & 15;
#pragma unroll
      for (int ks = 0; ks < 8; ++ks) {
        int chunk = ks * 4 + (l >> 4);
        a1[ks] = *(const bf16x8*)&hsum[arow * 256 + ((chunk ^ (arow & 7)) * 8)];
      }
    }
#pragma unroll
    for (int i = 0; i < 3; ++i) {
      int tt = w * 3 + i;
      int s = tt >> 2, t = tt & 3;
      f32x4 acc = (f32x4){0.f, 0.f, 0.f, 0.f};
#pragma unroll
      for (int ks = 0; ks < 8; ++ks)
        acc = __builtin_amdgcn_mfma_f32_16x16x32_bf16(a1[ks], w1[i][ks], acc, 0, 0, 0);
      int colg = colg_[i];
      float bias = b1g_[i];
#pragma unroll
      for (int r = 0; r < 4; ++r) {
        int nodeL = (l >> 4) * 4 + r;
        float v = acc[r] + gx[(size_t)(node0 + nodeL) * 1024 + colg] + bias;
        iouA[nodeL * 196 + s * 64 + t * 16 + (l & 15)] = (s < 2) ? fsig(v) : ftanh(v);
      }
    }
    __syncthreads();

    // ---- GEMM2 (per-child forget gates) + combine + coherent stores ----
    bf16x8 a2[8];
    {
      int arow = w * 16 + (l & 15);
#pragma unroll
      for (int ks = 0; ks < 8; ++ks) {
        int chunk = ks * 4 + (l >> 4);
        a2[ks] = *(const bf16x8*)&hch[arow * 256 + ((chunk ^ (arow & 7)) * 8)];
      }
    }
    const int nodeL = w * 4 + (l >> 4);
    const int node = node0 + nodeL;
#pragma unroll
    for (int nt = 0; nt < 4; ++nt) {
      int hl = nt * 16 + (l & 15);  // local h 0..63
      int hcol = h0 + hl;
      f32x4 acc = (f32x4){0.f, 0.f, 0.f, 0.f};
#pragma unroll
      for (int ks = 0; ks < 8; ++ks)
        acc = __builtin_amdgcn_mfma_f32_16x16x32_bf16(a2[ks], w2[nt][ks], acc, 0, 0, 0);
      float fx = gx[(size_t)node * 1024 + 768 + hcol] + b2g_[nt];
      float fcsum = 0.f;
#pragma unroll
      for (int r = 0; r < 4; ++r)
        fcsum += fsig(fx + acc[r]) * c_lds[(nodeL * 4 + r) * 68 + hl];
      float ig = iouA[nodeL * 196 + hl];
      float og = iouA[nodeL * 196 + 64 + hl];
      float ug = iouA[nodeL * 196 + 128 + hl];
      float cnew = ig * ug + fcsum;
      float hnew = og * ftanh(cnew);
      hout[(size_t)node * 256 + hcol] = hnew;
      gstore_dw(cb + (size_t)node * 256 + hcol, cnew);
      gstore_sh(hb + (size_t)node * 256 + hcol, f2bf(hnew));
    }
    asm volatile("s_waitcnt vmcnt(0)" ::: "memory");  // our coherent stores done
    __syncthreads();                                   // whole block done
    if (tid == 0)
      __hip_atomic_fetch_add(flags + ((level << 6) + ntile), 1u,
                             __ATOMIC_RELAXED, __HIP_MEMORY_SCOPE_AGENT);
  }
}

// ---------------- launch ----------------
extern "C" void kernel_launch(void* const* d_in, const int* in_sizes, int n_in,
                              void* d_out, int out_size, void* d_ws, size_t ws_size,
                              hipStream_t stream) {
  const float* x = (const float*)d_in[0];
  const int* children = (const int*)d_in[1];
  const float* Wioux = (const float*)d_in[2];
  const float* bioux = (const float*)d_in[3];
  const float* Wiouh = (const float*)d_in[4];
  const float* biouh = (const float*)d_in[5];
  const float* Wfx = (const float*)d_in[6];
  const float* bfx = (const float*)d_in[7];
  const float* Wfh = (const float*)d_in[8];
  const float* bfh = (const float*)d_in[9];

  char* ws = (char*)d_ws;
  u16* xb = (u16*)(ws + 0);              // 33,554,432 B
  float* gx = (float*)(ws + 33554432);   // 67,108,864 B
  u16* hb = (u16*)(ws + 100663296);      //  8,388,608 B
  float* cb = (float*)(ws + 109051904);  // 16,777,216 B
  u16* Wxb = (u16*)(ws + 125829120);     //  2,097,152 B
  u16* Whb = (u16*)(ws + 127926272);     //    524,288 B
  float* b1 = (float*)(ws + 128450560);  //      4,096 B
  float* b2 = (float*)(ws + 128454656);  //      4,096 B
  u32* flags = (u32*)(ws + 128458752);   //      4,096 B (1024 tile flags)
  float* hout = (float*)d_out;

  hipMemsetAsync(flags, 0, 4096, stream);
  k_cvt_x<<<8192, 256, 0, stream>>>(x, xb);
  k_cvt_w<<<641, 256, 0, stream>>>(Wioux, Wfx, Wiouh, Wfh, bioux, bfx, biouh, bfh,
                                   Wxb, Whb, b1, b2);
  k_gemm1<<<dim3(8, 128), 256, 0, stream>>>(xb, Wxb, b1, gx);
  k_levels<<<256, 256, 0, stream>>>(children, gx, Whb, b2, hb, cb, hout, flags);
}